// Round 12
// baseline (505.566 us; speedup 1.0000x reference)
//
#include <hip/hip_runtime.h>
#include <hip/hip_bf16.h>
#include <stdint.h>

typedef unsigned short u16;
typedef unsigned int u32;
typedef __attribute__((ext_vector_type(8))) __bf16 bf16x8;
typedef __attribute__((ext_vector_type(4))) float f32x4;
typedef __attribute__((ext_vector_type(4))) unsigned int u32x4;

#define NEG_SLOPE 0.2f
#define SCT 256   // threads per scan block
#define SCC 16    // elements per scan thread

__device__ __forceinline__ float bf2f(u16 u) {
    return __uint_as_float(((u32)u) << 16);
}
__device__ __forceinline__ u16 f2bf(float f) {
    u32 x = __float_as_uint(f);
    u32 r = (x + 0x7fffu + ((x >> 16) & 1u)) >> 16;  // round-to-nearest-even
    return (u16)r;
}
__device__ __forceinline__ float edge_w(float v) {
    v = v > 0.f ? v : NEG_SLOPE * v;  // LeakyReLU
    return __expf(v);
}

// ---------------- k0: deg=0 + projected attention vectors ----------------
// ws1[hd][k] = sum_c W1[k, hd*64+c] * a1s[hd*64+c]  (likewise wd1 with a1d)
__global__ void k0_kernel(const float* __restrict__ W1, const float* __restrict__ a1s,
                          const float* __restrict__ a1d, float* __restrict__ ws1,
                          float* __restrict__ wd1, int* __restrict__ deg, int N) {
    int t = blockIdx.x * blockDim.x + threadIdx.x;
    if (t < N) {
        deg[t] = 0;
    } else if (t < N + 2048) {
        int i = t - N;
        int which = i >> 10;        // 0: src, 1: dst
        int hd = (i & 1023) >> 7;   // head
        int k = i & 127;            // input channel
        const float* av = which ? a1d : a1s;
        float s = 0.f;
#pragma unroll 8
        for (int c = 0; c < 64; c++) s = fmaf(W1[k * 512 + hd * 64 + c], av[hd * 64 + c], s);
        (which ? wd1 : ws1)[hd * 128 + k] = s;
    }
}

// ---------------- setup: hist(+rank) + transpose W1/W2 ----------------
// The histogram's atomicAdd return value IS the edge's rank within its dst
// bucket — stored to rank[] so the scatter pass needs no atomics at all.
__global__ void setup_kernel(const int* __restrict__ dst, int* __restrict__ deg,
                             int* __restrict__ rank,
                             const float* __restrict__ W1, const float* __restrict__ W2,
                             u16* __restrict__ w1t, u16* __restrict__ w2t,
                             int E, int N) {
    int t = blockIdx.x * blockDim.x + threadIdx.x;
    int rE = E;
    int r1 = rE + 512 * 128;       // W1[128,512] -> w1t[512,128]
    int r2 = r1 + 64 * 512;        // W2[512,40] -> w2t[64,512] (rows 40..63 zero)
    if (t < rE) {
        rank[t] = atomicAdd(&deg[dst[t]], 1);
    } else if (t < r1) {
        int i = t - rE;
        int nn = i >> 7, k = i & 127;
        w1t[i] = f2bf(W1[k * 512 + nn]);
    } else if (t < r2) {
        int i = t - r1;
        int nn = i >> 9, k = i & 511;
        w2t[i] = (nn < 40) ? f2bf(W2[k * 40 + nn]) : (u16)0;
    }
}

// ---------------- 3-phase multi-block exclusive scan of (deg[i]+1) ----------------
__global__ void scanA_kernel(const int* __restrict__ deg, int* __restrict__ tsum, int N) {
    int t = blockIdx.x * SCT + threadIdx.x;
    int beg = t * SCC;
    int end = beg + SCC; if (end > N) end = N;
    int s = 0;
    for (int i = beg; i < end; i++) s += deg[i] + 1;  // +1 self loop
    tsum[t] = (beg < N) ? s : 0;
}

__global__ void scanB_kernel(int* __restrict__ tsum, int* __restrict__ offsets, int T, int N) {
    __shared__ int s[1024];
    int t = threadIdx.x;
    int chunk = (T + 1023) / 1024;
    int beg = t * chunk; if (beg > T) beg = T;
    int end = beg + chunk; if (end > T) end = T;
    int sum = 0;
    for (int i = beg; i < end; i++) sum += tsum[i];
    s[t] = sum;
    __syncthreads();
    for (int off = 1; off < 1024; off <<= 1) {
        int v = (t >= off) ? s[t - off] : 0;
        __syncthreads();
        s[t] += v;
        __syncthreads();
    }
    int run = s[t] - sum;  // exclusive prefix of this thread's chunk
    for (int i = beg; i < end; i++) {
        int v = tsum[i];
        tsum[i] = run;
        run += v;
    }
    if (t == 1023) offsets[N] = s[1023];  // grand total
}

__global__ void scanC_kernel(const int* __restrict__ deg, const int* __restrict__ tbase,
                             int* __restrict__ offsets, int N) {
    int t = blockIdx.x * SCT + threadIdx.x;
    int beg = t * SCC;
    int end = beg + SCC; if (end > N) end = N;
    int run = tbase[t];
    for (int i = beg; i < end; i++) {
        offsets[i] = run;
        run += deg[i] + 1;
    }
}

// scatter (atomic-free: idx = offs[dst] + precomputed rank) + fused logits1
// (als1/ald1 = x . ws1/wd1 per (node, head), fp32 x)
__global__ void scatter_kernel(const int* __restrict__ src, const int* __restrict__ dst,
                               const int* __restrict__ rank, const int* __restrict__ offs,
                               const int* __restrict__ deg, int* __restrict__ esrc,
                               const f32x4* __restrict__ xf,
                               const float* __restrict__ ws1, const float* __restrict__ wd1,
                               float* __restrict__ als1, float* __restrict__ ald1,
                               int E, int N) {
    int t = blockIdx.x * blockDim.x + threadIdx.x;
    if (t < E) {
        int d = dst[t];
        esrc[offs[d] + rank[t]] = src[t];
    } else if (t < E + N) {
        int i = t - E;
        esrc[offs[i] + deg[i]] = i;  // self loop takes the last slot
    } else if (t < E + N + 8 * N) {
        int idx = t - E - N;
        int n = idx >> 3, hd = idx & 7;
        const f32x4* xr = xf + (size_t)n * 32;
        const float* wsr = ws1 + hd * 128;
        const float* wdr = wd1 + hd * 128;
        float s = 0.f, d = 0.f;
#pragma unroll 8
        for (int kk = 0; kk < 32; kk++) {
            f32x4 v = xr[kk];
#pragma unroll
            for (int q = 0; q < 4; q++) {
                s = fmaf(v[q], wsr[4 * kk + q], s);
                d = fmaf(v[q], wdr[4 * kk + q], d);
            }
        }
        als1[idx] = s;
        ald1[idx] = d;
    }
}

// ---------------- agg1x: per-head weighted x aggregation (fp32 x) ----------------
// y[n, hh, :] = (sum_e alpha^hd_e x[src]) / z_hd. One wave per node; lane =
// (head-group, chan-group). fp32 x: no bf16->f32 converts in the hot loop
// (x = 25.6 MB, LLC-resident). 2-edge unroll x 4 float4 = 8 loads in flight.
template <int NH>
__global__ __launch_bounds__(256) void agg1x_kernel(
    const int* __restrict__ offs, const int* __restrict__ esrc,
    const f32x4* __restrict__ xf, const float* __restrict__ als,
    const float* __restrict__ ald, u16* __restrict__ y, int N, int hd0) {
    constexpr int LPH = 64 / NH;    // lanes per head
    constexpr int CPL = 128 / LPH;  // channels per lane
    constexpr int NF4 = CPL / 4;    // float4 per lane per row
    int wid = blockIdx.x * 4 + (threadIdx.x >> 6);
    if (wid >= N) return;
    int lane = threadIdx.x & 63;
    int hd_l = lane / LPH;
    int chg = lane % LPH;
    int b = offs[wid], e = offs[wid + 1];
    float ad = ald[wid * 8 + hd0 + hd_l];
    float acc0[CPL] = {}, acc1[CPL] = {};
    float zs = 0.f;
    const f32x4* xr = xf + chg * NF4;
    for (int jb = b; jb < e; jb += 64) {
        int nk = min(64, e - jb);
        int my = (jb + lane < e) ? esrc[jb + lane] : 0;
        int k = 0;
        for (; k + 2 <= nk; k += 2) {
            int s0 = __shfl(my, k), s1 = __shfl(my, k + 1);
            f32x4 a0[NF4], a1[NF4];
#pragma unroll
            for (int j = 0; j < NF4; j++) {
                a0[j] = xr[(size_t)s0 * 32 + j];
                a1[j] = xr[(size_t)s1 * 32 + j];
            }
            float l0 = als[s0 * 8 + hd0 + hd_l];
            float l1 = als[s1 * 8 + hd0 + hd_l];
            float w0 = edge_w(l0 + ad), w1 = edge_w(l1 + ad);
            zs += w0 + w1;
#pragma unroll
            for (int j = 0; j < NF4; j++) {
#pragma unroll
                for (int q = 0; q < 4; q++) {
                    acc0[j * 4 + q] = fmaf(w0, a0[j][q], acc0[j * 4 + q]);
                    acc1[j * 4 + q] = fmaf(w1, a1[j][q], acc1[j * 4 + q]);
                }
            }
        }
        for (; k < nk; k++) {
            int s = __shfl(my, k);
            f32x4 a[NF4];
#pragma unroll
            for (int j = 0; j < NF4; j++) a[j] = xr[(size_t)s * 32 + j];
            float w = edge_w(als[s * 8 + hd0 + hd_l] + ad);
            zs += w;
#pragma unroll
            for (int j = 0; j < NF4; j++)
#pragma unroll
                for (int q = 0; q < 4; q++)
                    acc0[j * 4 + q] = fmaf(w, a[j][q], acc0[j * 4 + q]);
        }
    }
    float zi = 1.f / zs;  // >0: self loop guarantees an edge
    u16 ob[CPL];
#pragma unroll
    for (int c = 0; c < CPL; c++) ob[c] = f2bf((acc0[c] + acc1[c]) * zi);
    u16* dst = y + ((size_t)wid * NH + hd_l) * 128 + chg * CPL;
#pragma unroll
    for (int j = 0; j < CPL / 8; j++) {
        u32x4 pv;
        pv.x = (u32)ob[j * 8 + 0] | ((u32)ob[j * 8 + 1] << 16);
        pv.y = (u32)ob[j * 8 + 2] | ((u32)ob[j * 8 + 3] << 16);
        pv.z = (u32)ob[j * 8 + 4] | ((u32)ob[j * 8 + 5] << 16);
        pv.w = (u32)ob[j * 8 + 6] | ((u32)ob[j * 8 + 7] << 16);
        __builtin_nontemporal_store(pv, (u32x4*)dst + j);
    }
}

// ---------------- gemm1b: per-head y @ W1_head + b1 -> relu -> h2 ----------------
template <int NH>
__global__ __launch_bounds__(256) void gemm1b_kernel(
    const u16* __restrict__ y, const u16* __restrict__ w1t,
    const float* __restrict__ b1, u16* __restrict__ h2, int M, int hd0) {
    constexpr int LDT = 136;  // 128 + 8 pad
    __shared__ u16 As[64 * LDT];
    __shared__ u16 Bs[64 * LDT];
    const int tid = threadIdx.x;
    const int r0 = blockIdx.x * 64;
    const int hh = blockIdx.y;
    const int head = hd0 + hh;
    const int lane = tid & 63, w = tid >> 6;
    const int quad = lane >> 4, l16 = lane & 15;
    {
        int row = tid >> 2, q = tid & 3;
        int gr = r0 + row;
        uint4 v0 = make_uint4(0u, 0u, 0u, 0u), v1 = v0, v2 = v0, v3 = v0;
        if (gr < M) {
            const u16* p = y + ((size_t)gr * NH + hh) * 128 + q * 32;
            v0 = *(const uint4*)p;
            v1 = *(const uint4*)(p + 8);
            v2 = *(const uint4*)(p + 16);
            v3 = *(const uint4*)(p + 24);
        }
        u16* d = &As[row * LDT + q * 32];
        *(uint4*)(d + 0) = v0;
        *(uint4*)(d + 8) = v1;
        *(uint4*)(d + 16) = v2;
        *(uint4*)(d + 24) = v3;
    }
    {
        int row = tid >> 2, q = tid & 3;
        const u16* p = w1t + ((size_t)(head * 64 + row)) * 128 + q * 32;
        uint4 v0 = *(const uint4*)p;
        uint4 v1 = *(const uint4*)(p + 8);
        uint4 v2 = *(const uint4*)(p + 16);
        uint4 v3 = *(const uint4*)(p + 24);
        u16* d = &Bs[row * LDT + q * 32];
        *(uint4*)(d + 0) = v0;
        *(uint4*)(d + 8) = v1;
        *(uint4*)(d + 16) = v2;
        *(uint4*)(d + 24) = v3;
    }
    __syncthreads();
    f32x4 acc[4] = {};
#pragma unroll
    for (int kst = 0; kst < 4; kst++) {
        uint4 va = *(const uint4*)&As[(w * 16 + l16) * LDT + kst * 32 + quad * 8];
        bf16x8 af = __builtin_bit_cast(bf16x8, va);
#pragma unroll
        for (int ni = 0; ni < 4; ni++) {
            uint4 vb = *(const uint4*)&Bs[(ni * 16 + l16) * LDT + kst * 32 + quad * 8];
            bf16x8 bf = __builtin_bit_cast(bf16x8, vb);
            acc[ni] = __builtin_amdgcn_mfma_f32_16x16x32_bf16(af, bf, acc[ni], 0, 0, 0);
        }
    }
#pragma unroll
    for (int r = 0; r < 4; r++) {
        int gr = r0 + w * 16 + quad * 4 + r;
        if (gr >= M) continue;
#pragma unroll
        for (int ni = 0; ni < 4; ni++) {
            int gc = head * 64 + ni * 16 + l16;
            float v = acc[ni][r] + b1[gc];
            v = v > 0.f ? v : 0.f;  // inter-layer ReLU
            h2[(size_t)gr * 512 + gc] = f2bf(v);
        }
    }
}

// ---------------- GEMM2 (h2 @ W2 -> g fp32) + fused logits2 ----------------
__global__ __launch_bounds__(256) void gemm2_fused(
    const u16* __restrict__ A, const u16* __restrict__ Bt,
    const float* __restrict__ a2s, const float* __restrict__ a2d,
    float* __restrict__ g, float* __restrict__ als, float* __restrict__ ald, int M) {
    constexpr int LDT = 136;  // 128 + 8 pad
    __shared__ u16 As[64 * LDT];
    __shared__ u16 Bs[64 * LDT];
    const int tid = threadIdx.x;
    const int r0 = blockIdx.x * 64;
    const int lane = tid & 63, w = tid >> 6;
    const int quad = lane >> 4, l16 = lane & 15;
    f32x4 acc[4] = {};

    float asc[4], adc[4];
#pragma unroll
    for (int ni = 0; ni < 4; ni++) {
        int gc = ni * 16 + l16;
        asc[ni] = (gc < 40) ? a2s[gc] : 0.f;
        adc[ni] = (gc < 40) ? a2d[gc] : 0.f;
    }

    for (int kc = 0; kc < 512; kc += 128) {
        {
            int row = tid >> 2, q = tid & 3;
            int gr = r0 + row;
            uint4 v0 = make_uint4(0u, 0u, 0u, 0u), v1 = v0, v2 = v0, v3 = v0;
            if (gr < M) {
                const u16* p = A + (size_t)gr * 512 + kc + q * 32;
                v0 = *(const uint4*)p;
                v1 = *(const uint4*)(p + 8);
                v2 = *(const uint4*)(p + 16);
                v3 = *(const uint4*)(p + 24);
            }
            u16* d = &As[row * LDT + q * 32];
            *(uint4*)(d + 0) = v0;
            *(uint4*)(d + 8) = v1;
            *(uint4*)(d + 16) = v2;
            *(uint4*)(d + 24) = v3;
        }
        {
            int row = tid >> 2, q = tid & 3;
            const u16* p = Bt + (size_t)row * 512 + kc + q * 32;
            uint4 v0 = *(const uint4*)p;
            uint4 v1 = *(const uint4*)(p + 8);
            uint4 v2 = *(const uint4*)(p + 16);
            uint4 v3 = *(const uint4*)(p + 24);
            u16* d = &Bs[row * LDT + q * 32];
            *(uint4*)(d + 0) = v0;
            *(uint4*)(d + 8) = v1;
            *(uint4*)(d + 16) = v2;
            *(uint4*)(d + 24) = v3;
        }
        __syncthreads();
#pragma unroll
        for (int kst = 0; kst < 4; kst++) {
            uint4 va = *(const uint4*)&As[(w * 16 + l16) * LDT + kst * 32 + quad * 8];
            bf16x8 af = __builtin_bit_cast(bf16x8, va);
#pragma unroll
            for (int ni = 0; ni < 4; ni++) {
                uint4 vb = *(const uint4*)&Bs[(ni * 16 + l16) * LDT + kst * 32 + quad * 8];
                bf16x8 bf = __builtin_bit_cast(bf16x8, vb);
                acc[ni] = __builtin_amdgcn_mfma_f32_16x16x32_bf16(af, bf, acc[ni], 0, 0, 0);
            }
        }
        __syncthreads();
    }
#pragma unroll
    for (int r = 0; r < 4; r++) {
        int gr = r0 + w * 16 + quad * 4 + r;
        float ps = 0.f, pd = 0.f;
#pragma unroll
        for (int ni = 0; ni < 4; ni++) {
            float v = acc[ni][r];
            ps = fmaf(v, asc[ni], ps);
            pd = fmaf(v, adc[ni], pd);
            int gc = ni * 16 + l16;
            if (gr < M && gc < 40) g[(size_t)gr * 40 + gc] = v;
        }
#pragma unroll
        for (int m = 8; m >= 1; m >>= 1) {
            ps += __shfl_xor(ps, m);
            pd += __shfl_xor(pd, m);
        }
        if (l16 == 0 && gr < M) {
            als[gr] = ps;
            ald[gr] = pd;
        }
    }
}

// ---------------- fused softmax+aggregation, layer 2 ----------------
__global__ __launch_bounds__(256) void agg2_fused(
    const int* __restrict__ offs, const int* __restrict__ esrc,
    const float* __restrict__ g, const float* __restrict__ als,
    const float* __restrict__ ald, const float* __restrict__ b2,
    float* __restrict__ out, int N) {
    int wid = blockIdx.x * 4 + (threadIdx.x >> 6);
    if (wid >= N) return;
    int lane = threadIdx.x & 63;
    int b = offs[wid], e = offs[wid + 1];
    float ad = ald[wid];
    float acc0 = 0.f, acc1 = 0.f, acc2 = 0.f, acc3 = 0.f, zs = 0.f;
    bool active = lane < 40;
    for (int jb = b; jb < e; jb += 64) {
        int nk = min(64, e - jb);
        int my = (jb + lane < e) ? esrc[jb + lane] : 0;
        int k = 0;
        for (; k + 8 <= nk; k += 8) {
            int s0 = __shfl(my, k + 0), s1 = __shfl(my, k + 1);
            int s2 = __shfl(my, k + 2), s3 = __shfl(my, k + 3);
            int s4 = __shfl(my, k + 4), s5 = __shfl(my, k + 5);
            int s6 = __shfl(my, k + 6), s7 = __shfl(my, k + 7);
            float g0 = active ? g[(size_t)s0 * 40 + lane] : 0.f;
            float g1 = active ? g[(size_t)s1 * 40 + lane] : 0.f;
            float g2 = active ? g[(size_t)s2 * 40 + lane] : 0.f;
            float g3 = active ? g[(size_t)s3 * 40 + lane] : 0.f;
            float g4 = active ? g[(size_t)s4 * 40 + lane] : 0.f;
            float g5 = active ? g[(size_t)s5 * 40 + lane] : 0.f;
            float g6 = active ? g[(size_t)s6 * 40 + lane] : 0.f;
            float g7 = active ? g[(size_t)s7 * 40 + lane] : 0.f;
            float w0 = edge_w(als[s0] + ad), w1 = edge_w(als[s1] + ad);
            float w2 = edge_w(als[s2] + ad), w3 = edge_w(als[s3] + ad);
            float w4 = edge_w(als[s4] + ad), w5 = edge_w(als[s5] + ad);
            float w6 = edge_w(als[s6] + ad), w7 = edge_w(als[s7] + ad);
            zs += ((w0 + w1) + (w2 + w3)) + ((w4 + w5) + (w6 + w7));
            acc0 = fmaf(w0, g0, acc0);
            acc1 = fmaf(w1, g1, acc1);
            acc2 = fmaf(w2, g2, acc2);
            acc3 = fmaf(w3, g3, acc3);
            acc0 = fmaf(w4, g4, acc0);
            acc1 = fmaf(w5, g5, acc1);
            acc2 = fmaf(w6, g6, acc2);
            acc3 = fmaf(w7, g7, acc3);
        }
        for (; k < nk; k++) {
            int s = __shfl(my, k);
            float gv = active ? g[(size_t)s * 40 + lane] : 0.f;
            float w = edge_w(als[s] + ad);
            zs += w;
            acc0 = fmaf(w, gv, acc0);
        }
    }
    if (active)
        out[(size_t)wid * 40 + lane] = ((acc0 + acc1) + (acc2 + acc3)) / zs + b2[lane];
}

// ---------------- host launch ----------------

extern "C" void kernel_launch(void* const* d_in, const int* in_sizes, int n_in,
                              void* d_out, int out_size, void* d_ws, size_t ws_size,
                              hipStream_t stream) {
    const float* x   = (const float*)d_in[0];
    const int*   ei  = (const int*)d_in[1];
    const float* W1  = (const float*)d_in[2];
    const float* a1s = (const float*)d_in[3];
    const float* a1d = (const float*)d_in[4];
    const float* b1  = (const float*)d_in[5];
    const float* W2  = (const float*)d_in[6];
    const float* a2s = (const float*)d_in[7];
    const float* a2d = (const float*)d_in[8];
    const float* b2  = (const float*)d_in[9];
    float* out = (float*)d_out;

    const int F = 128;
    const int N = in_sizes[0] / F;
    const int E = in_sizes[1] / 2;
    const int ET = E + N;
    const int Npad = (N + 63) & ~63;
    const int nScanBlk = (N + SCT * SCC - 1) / (SCT * SCC);
    const int T = nScanBlk * SCT;

    char* ws = (char*)d_ws;
    size_t off = 0;
    auto alloc = [&](size_t bytes) -> char* {
        char* p = ws + off;
        off += (bytes + 255) & ~(size_t)255;
        return p;
    };
    int*   esrc = (int*)alloc((size_t)ET * 4);
    int*   rank = (int*)alloc((size_t)E * 4);
    float* als1 = (float*)alloc((size_t)N * 8 * 4);
    float* ald1 = (float*)alloc((size_t)N * 8 * 4);
    float* als2 = (float*)alloc((size_t)N * 4);
    float* ald2 = (float*)alloc((size_t)N * 4);
    int*   deg  = (int*)alloc((size_t)N * 4);
    int*   offs = (int*)alloc((size_t)(N + 1) * 4);
    int*   tsum = (int*)alloc((size_t)T * 4);
    u16*   w1t  = (u16*)alloc((size_t)512 * 128 * 2);
    u16*   w2t  = (u16*)alloc((size_t)64 * 512 * 2);
    float* ws1  = (float*)alloc((size_t)1024 * 4);
    float* wd1  = (float*)alloc((size_t)1024 * 4);
    u16*   h2   = (u16*)alloc((size_t)N * 512 * 2);
    // y sized by pass count (1 pass of 8 heads if workspace allows, else 2x4)
    size_t y8 = (size_t)Npad * 8 * 128 * 2;
    size_t y4 = (size_t)Npad * 4 * 128 * 2;
    int NHp = (off + y8 + 4096 <= ws_size) ? 8 : 4;
    u16* y = (u16*)alloc(NHp == 8 ? y8 : y4);
    float* g = (float*)y;  // g [N,40] fp32 aliases y (y dead after gemm1b)

    const int TPB = 256;
    const int* e_src = ei;
    const int* e_dst = ei + E;

    // CSR + prep
    k0_kernel<<<(N + 2048 + TPB - 1) / TPB, TPB, 0, stream>>>(W1, a1s, a1d, ws1, wd1, deg, N);
    int setup_n = E + 512 * 128 + 64 * 512;
    setup_kernel<<<(setup_n + TPB - 1) / TPB, TPB, 0, stream>>>(
        e_dst, deg, rank, W1, W2, w1t, w2t, E, N);
    scanA_kernel<<<nScanBlk, SCT, 0, stream>>>(deg, tsum, N);
    scanB_kernel<<<1, 1024, 0, stream>>>(tsum, offs, T, N);
    scanC_kernel<<<nScanBlk, SCT, 0, stream>>>(deg, tsum, offs, N);
    int scat_n = E + N + 8 * N;
    scatter_kernel<<<(scat_n + TPB - 1) / TPB, TPB, 0, stream>>>(
        e_src, e_dst, rank, offs, deg, esrc, (const f32x4*)x, ws1, wd1, als1, ald1, E, N);

    // layer 1: aggregate x per head, then block-diagonal GEMM
    if (NHp == 8) {
        agg1x_kernel<8><<<(N + 3) / 4, 256, 0, stream>>>(
            offs, esrc, (const f32x4*)x, als1, ald1, y, N, 0);
        gemm1b_kernel<8><<<dim3((N + 63) / 64, 8), 256, 0, stream>>>(y, w1t, b1, h2, N, 0);
    } else {
        for (int p = 0; p < 2; p++) {
            agg1x_kernel<4><<<(N + 3) / 4, 256, 0, stream>>>(
                offs, esrc, (const f32x4*)x, als1, ald1, y, N, p * 4);
            gemm1b_kernel<4><<<dim3((N + 63) / 64, 4), 256, 0, stream>>>(y, w1t, b1, h2, N, p * 4);
        }
    }

    // layer 2
    gemm2_fused<<<(N + 63) / 64, 256, 0, stream>>>(h2, w2t, a2s, a2d, g, als2, ald2, N);
    agg2_fused<<<(N + 3) / 4, 256, 0, stream>>>(offs, esrc, g, als2, ald2, b2, out, N);
}

// Round 13
// 432.350 us; speedup vs baseline: 1.1693x; 1.1693x over previous
//
#include <hip/hip_runtime.h>
#include <hip/hip_bf16.h>
#include <stdint.h>

typedef unsigned short u16;
typedef unsigned int u32;
typedef __attribute__((ext_vector_type(8))) __bf16 bf16x8;
typedef __attribute__((ext_vector_type(4))) float f32x4;

#define NEG_SLOPE 0.2f
#define SCT 256   // threads per scan block
#define SCC 16    // elements per scan thread

__device__ __forceinline__ float bf2f(u16 u) {
    return __uint_as_float(((u32)u) << 16);
}
__device__ __forceinline__ u16 f2bf(float f) {
    u32 x = __float_as_uint(f);
    u32 r = (x + 0x7fffu + ((x >> 16) & 1u)) >> 16;  // round-to-nearest-even
    return (u16)r;
}
__device__ __forceinline__ float edge_w(float v) {
    v = v > 0.f ? v : NEG_SLOPE * v;  // LeakyReLU
    return __expf(v);
}

// ---------------- k0: deg=0 + projected attention vectors ----------------
// ws1[hd][k] = sum_c W1[k, hd*64+c] * a1s[hd*64+c]  (likewise wd1 with a1d)
__global__ void k0_kernel(const float* __restrict__ W1, const float* __restrict__ a1s,
                          const float* __restrict__ a1d, float* __restrict__ ws1,
                          float* __restrict__ wd1, int* __restrict__ deg, int N) {
    int t = blockIdx.x * blockDim.x + threadIdx.x;
    if (t < N) {
        deg[t] = 0;
    } else if (t < N + 2048) {
        int i = t - N;
        int which = i >> 10;        // 0: src, 1: dst
        int hd = (i & 1023) >> 7;   // head
        int k = i & 127;            // input channel
        const float* av = which ? a1d : a1s;
        float s = 0.f;
#pragma unroll 8
        for (int c = 0; c < 64; c++) s = fmaf(W1[k * 512 + hd * 64 + c], av[hd * 64 + c], s);
        (which ? wd1 : ws1)[hd * 128 + k] = s;
    }
}

// ---------------- setup: hist(+rank) + cast x->bf16 + transpose W1/W2 ----------------
// The histogram's atomicAdd return value IS the edge's rank within its dst
// bucket — stored to rank[] so the scatter pass needs no atomics at all.
__global__ void setup_kernel(const int* __restrict__ dst, int* __restrict__ deg,
                             int* __restrict__ rank,
                             const float* __restrict__ x, const float* __restrict__ W1,
                             const float* __restrict__ W2, u16* __restrict__ xb,
                             u16* __restrict__ w1t, u16* __restrict__ w2t,
                             int E, int N) {
    int t = blockIdx.x * blockDim.x + threadIdx.x;
    int rE = E;
    int r1 = rE + N * 32;          // x cast, float4 granules
    int r2 = r1 + 512 * 128;       // W1[128,512] -> w1t[512,128]
    int r3 = r2 + 64 * 512;        // W2[512,40] -> w2t[64,512] (rows 40..63 zero)
    if (t < rE) {
        rank[t] = atomicAdd(&deg[dst[t]], 1);
    } else if (t < r1) {
        int base = (t - rE) * 4;
        float4 v = *(const float4*)(x + base);
        xb[base + 0] = f2bf(v.x);
        xb[base + 1] = f2bf(v.y);
        xb[base + 2] = f2bf(v.z);
        xb[base + 3] = f2bf(v.w);
    } else if (t < r2) {
        int i = t - r1;
        int nn = i >> 7, k = i & 127;
        w1t[i] = f2bf(W1[k * 512 + nn]);
    } else if (t < r3) {
        int i = t - r2;
        int nn = i >> 9, k = i & 511;
        w2t[i] = (nn < 40) ? f2bf(W2[k * 40 + nn]) : (u16)0;
    }
}

// ---------------- 3-phase multi-block exclusive scan of (deg[i]+1) ----------------
__global__ void scanA_kernel(const int* __restrict__ deg, int* __restrict__ tsum, int N) {
    int t = blockIdx.x * SCT + threadIdx.x;
    int beg = t * SCC;
    int end = beg + SCC; if (end > N) end = N;
    int s = 0;
    for (int i = beg; i < end; i++) s += deg[i] + 1;  // +1 self loop
    tsum[t] = (beg < N) ? s : 0;
}

__global__ void scanB_kernel(int* __restrict__ tsum, int* __restrict__ offsets, int T, int N) {
    __shared__ int s[1024];
    int t = threadIdx.x;
    int chunk = (T + 1023) / 1024;
    int beg = t * chunk; if (beg > T) beg = T;
    int end = beg + chunk; if (end > T) end = T;
    int sum = 0;
    for (int i = beg; i < end; i++) sum += tsum[i];
    s[t] = sum;
    __syncthreads();
    for (int off = 1; off < 1024; off <<= 1) {
        int v = (t >= off) ? s[t - off] : 0;
        __syncthreads();
        s[t] += v;
        __syncthreads();
    }
    int run = s[t] - sum;  // exclusive prefix of this thread's chunk
    for (int i = beg; i < end; i++) {
        int v = tsum[i];
        tsum[i] = run;
        run += v;
    }
    if (t == 1023) offsets[N] = s[1023];  // grand total
}

__global__ void scanC_kernel(const int* __restrict__ deg, const int* __restrict__ tbase,
                             int* __restrict__ offsets, int N) {
    int t = blockIdx.x * SCT + threadIdx.x;
    int beg = t * SCC;
    int end = beg + SCC; if (end > N) end = N;
    int run = tbase[t];
    for (int i = beg; i < end; i++) {
        offsets[i] = run;
        run += deg[i] + 1;
    }
}

// scatter (atomic-free: idx = offs[dst] + precomputed rank) + fused logits1
// (als1/ald1 = xb . ws1/wd1 per (node, head))
__global__ void scatter_kernel(const int* __restrict__ src, const int* __restrict__ dst,
                               const int* __restrict__ rank, const int* __restrict__ offs,
                               const int* __restrict__ deg, int* __restrict__ esrc,
                               const u32* __restrict__ xb32,
                               const float* __restrict__ ws1, const float* __restrict__ wd1,
                               float* __restrict__ als1, float* __restrict__ ald1,
                               int E, int N) {
    int t = blockIdx.x * blockDim.x + threadIdx.x;
    if (t < E) {
        int d = dst[t];
        esrc[offs[d] + rank[t]] = src[t];
    } else if (t < E + N) {
        int i = t - E;
        esrc[offs[i] + deg[i]] = i;  // self loop takes the last slot
    } else if (t < E + N + 8 * N) {
        int idx = t - E - N;
        int n = idx >> 3, hd = idx & 7;
        const u32* xr = xb32 + (size_t)n * 64;
        const float* wsr = ws1 + hd * 128;
        const float* wdr = wd1 + hd * 128;
        float s = 0.f, d = 0.f;
#pragma unroll 8
        for (int kk = 0; kk < 64; kk++) {
            u32 v = xr[kk];
            float x0 = __uint_as_float(v << 16);
            float x1 = __uint_as_float(v & 0xffff0000u);
            s = fmaf(x0, wsr[2 * kk], fmaf(x1, wsr[2 * kk + 1], s));
            d = fmaf(x0, wdr[2 * kk], fmaf(x1, wdr[2 * kk + 1], d));
        }
        als1[idx] = s;
        ald1[idx] = d;
    }
}

// ---------------- agg1x: per-head weighted x aggregation (bf16 x) ----------------
// y[n, hh, :] = (sum_e alpha^hd_e x[src]) / z_hd. One wave per node; lane =
// (head-group, chan-group); wave reads the 256B bf16 x row per edge (dup
// addresses across head groups broadcast). 4-edge unroll; paired bf16 decode
// (shift / mask = 1 inst per channel); split accumulators halve dep chain.
// Regular (cacheable) y stores: y is write-once-read-once -> let LLC absorb.
template <int NH>
__global__ __launch_bounds__(256) void agg1x_kernel(
    const int* __restrict__ offs, const int* __restrict__ esrc,
    const uint4* __restrict__ xb4, const float* __restrict__ als,
    const float* __restrict__ ald, u16* __restrict__ y, int N, int hd0) {
    constexpr int LPH = 64 / NH;    // lanes per head
    constexpr int CPL = 128 / LPH;  // channels per lane
    constexpr int NU4 = CPL / 8;    // uint4 (8 bf16) per lane per row
    int wid = blockIdx.x * 4 + (threadIdx.x >> 6);
    if (wid >= N) return;
    int lane = threadIdx.x & 63;
    int hd_l = lane / LPH;
    int chg = lane % LPH;
    int b = offs[wid], e = offs[wid + 1];
    float ad = ald[wid * 8 + hd0 + hd_l];
    float acc0[CPL] = {}, acc1[CPL] = {};
    float zs = 0.f;
    const uint4* xr = xb4 + chg * NU4;
    for (int jb = b; jb < e; jb += 64) {
        int nk = min(64, e - jb);
        int my = (jb + lane < e) ? esrc[jb + lane] : 0;
        int k = 0;
        for (; k + 4 <= nk; k += 4) {
            int s0 = __shfl(my, k), s1 = __shfl(my, k + 1);
            int s2 = __shfl(my, k + 2), s3 = __shfl(my, k + 3);
            uint4 a0[NU4], a1[NU4], a2[NU4], a3[NU4];
#pragma unroll
            for (int j = 0; j < NU4; j++) {
                a0[j] = xr[(size_t)s0 * 16 + j];
                a1[j] = xr[(size_t)s1 * 16 + j];
                a2[j] = xr[(size_t)s2 * 16 + j];
                a3[j] = xr[(size_t)s3 * 16 + j];
            }
            float l0 = als[s0 * 8 + hd0 + hd_l];
            float l1 = als[s1 * 8 + hd0 + hd_l];
            float l2 = als[s2 * 8 + hd0 + hd_l];
            float l3 = als[s3 * 8 + hd0 + hd_l];
            float w0 = edge_w(l0 + ad), w1 = edge_w(l1 + ad);
            float w2 = edge_w(l2 + ad), w3 = edge_w(l3 + ad);
            zs += (w0 + w1) + (w2 + w3);
#pragma unroll
            for (int j = 0; j < NU4; j++) {
                const u32* q0 = (const u32*)&a0[j];
                const u32* q1 = (const u32*)&a1[j];
                const u32* q2 = (const u32*)&a2[j];
                const u32* q3 = (const u32*)&a3[j];
#pragma unroll
                for (int p = 0; p < 4; p++) {
                    int c = j * 8 + p * 2;
                    acc0[c]     = fmaf(w0, __uint_as_float(q0[p] << 16), acc0[c]);
                    acc0[c + 1] = fmaf(w0, __uint_as_float(q0[p] & 0xffff0000u), acc0[c + 1]);
                    acc1[c]     = fmaf(w1, __uint_as_float(q1[p] << 16), acc1[c]);
                    acc1[c + 1] = fmaf(w1, __uint_as_float(q1[p] & 0xffff0000u), acc1[c + 1]);
                    acc0[c]     = fmaf(w2, __uint_as_float(q2[p] << 16), acc0[c]);
                    acc0[c + 1] = fmaf(w2, __uint_as_float(q2[p] & 0xffff0000u), acc0[c + 1]);
                    acc1[c]     = fmaf(w3, __uint_as_float(q3[p] << 16), acc1[c]);
                    acc1[c + 1] = fmaf(w3, __uint_as_float(q3[p] & 0xffff0000u), acc1[c + 1]);
                }
            }
        }
        for (; k < nk; k++) {
            int s = __shfl(my, k);
            uint4 a[NU4];
#pragma unroll
            for (int j = 0; j < NU4; j++) a[j] = xr[(size_t)s * 16 + j];
            float w = edge_w(als[s * 8 + hd0 + hd_l] + ad);
            zs += w;
#pragma unroll
            for (int j = 0; j < NU4; j++) {
                const u32* q = (const u32*)&a[j];
#pragma unroll
                for (int p = 0; p < 4; p++) {
                    int c = j * 8 + p * 2;
                    acc0[c]     = fmaf(w, __uint_as_float(q[p] << 16), acc0[c]);
                    acc0[c + 1] = fmaf(w, __uint_as_float(q[p] & 0xffff0000u), acc0[c + 1]);
                }
            }
        }
    }
    float zi = 1.f / zs;  // >0: self loop guarantees an edge
    u16 ob[CPL];
#pragma unroll
    for (int c = 0; c < CPL; c++) ob[c] = f2bf((acc0[c] + acc1[c]) * zi);
    u16* dst = y + ((size_t)wid * NH + hd_l) * 128 + chg * CPL;
#pragma unroll
    for (int j = 0; j < CPL / 8; j++) {
        uint4 pv;
        pv.x = (u32)ob[j * 8 + 0] | ((u32)ob[j * 8 + 1] << 16);
        pv.y = (u32)ob[j * 8 + 2] | ((u32)ob[j * 8 + 3] << 16);
        pv.z = (u32)ob[j * 8 + 4] | ((u32)ob[j * 8 + 5] << 16);
        pv.w = (u32)ob[j * 8 + 6] | ((u32)ob[j * 8 + 7] << 16);
        *((uint4*)dst + j) = pv;  // cacheable: y is consumed once by gemm1b
    }
}

// ---------------- gemm1b: per-head y @ W1_head + b1 -> relu -> h2 ----------------
template <int NH>
__global__ __launch_bounds__(256) void gemm1b_kernel(
    const u16* __restrict__ y, const u16* __restrict__ w1t,
    const float* __restrict__ b1, u16* __restrict__ h2, int M, int hd0) {
    constexpr int LDT = 136;  // 128 + 8 pad
    __shared__ u16 As[64 * LDT];
    __shared__ u16 Bs[64 * LDT];
    const int tid = threadIdx.x;
    const int r0 = blockIdx.x * 64;
    const int hh = blockIdx.y;
    const int head = hd0 + hh;
    const int lane = tid & 63, w = tid >> 6;
    const int quad = lane >> 4, l16 = lane & 15;
    {
        int row = tid >> 2, q = tid & 3;
        int gr = r0 + row;
        uint4 v0 = make_uint4(0u, 0u, 0u, 0u), v1 = v0, v2 = v0, v3 = v0;
        if (gr < M) {
            const u16* p = y + ((size_t)gr * NH + hh) * 128 + q * 32;
            v0 = *(const uint4*)p;
            v1 = *(const uint4*)(p + 8);
            v2 = *(const uint4*)(p + 16);
            v3 = *(const uint4*)(p + 24);
        }
        u16* d = &As[row * LDT + q * 32];
        *(uint4*)(d + 0) = v0;
        *(uint4*)(d + 8) = v1;
        *(uint4*)(d + 16) = v2;
        *(uint4*)(d + 24) = v3;
    }
    {
        int row = tid >> 2, q = tid & 3;
        const u16* p = w1t + ((size_t)(head * 64 + row)) * 128 + q * 32;
        uint4 v0 = *(const uint4*)p;
        uint4 v1 = *(const uint4*)(p + 8);
        uint4 v2 = *(const uint4*)(p + 16);
        uint4 v3 = *(const uint4*)(p + 24);
        u16* d = &Bs[row * LDT + q * 32];
        *(uint4*)(d + 0) = v0;
        *(uint4*)(d + 8) = v1;
        *(uint4*)(d + 16) = v2;
        *(uint4*)(d + 24) = v3;
    }
    __syncthreads();
    f32x4 acc[4] = {};
#pragma unroll
    for (int kst = 0; kst < 4; kst++) {
        uint4 va = *(const uint4*)&As[(w * 16 + l16) * LDT + kst * 32 + quad * 8];
        bf16x8 af = __builtin_bit_cast(bf16x8, va);
#pragma unroll
        for (int ni = 0; ni < 4; ni++) {
            uint4 vb = *(const uint4*)&Bs[(ni * 16 + l16) * LDT + kst * 32 + quad * 8];
            bf16x8 bf = __builtin_bit_cast(bf16x8, vb);
            acc[ni] = __builtin_amdgcn_mfma_f32_16x16x32_bf16(af, bf, acc[ni], 0, 0, 0);
        }
    }
#pragma unroll
    for (int r = 0; r < 4; r++) {
        int gr = r0 + w * 16 + quad * 4 + r;
        if (gr >= M) continue;
#pragma unroll
        for (int ni = 0; ni < 4; ni++) {
            int gc = head * 64 + ni * 16 + l16;
            float v = acc[ni][r] + b1[gc];
            v = v > 0.f ? v : 0.f;  // inter-layer ReLU
            h2[(size_t)gr * 512 + gc] = f2bf(v);
        }
    }
}

// ---------------- GEMM2 (h2 @ W2 -> g fp32) + fused logits2 ----------------
__global__ __launch_bounds__(256) void gemm2_fused(
    const u16* __restrict__ A, const u16* __restrict__ Bt,
    const float* __restrict__ a2s, const float* __restrict__ a2d,
    float* __restrict__ g, float* __restrict__ als, float* __restrict__ ald, int M) {
    constexpr int LDT = 136;  // 128 + 8 pad
    __shared__ u16 As[64 * LDT];
    __shared__ u16 Bs[64 * LDT];
    const int tid = threadIdx.x;
    const int r0 = blockIdx.x * 64;
    const int lane = tid & 63, w = tid >> 6;
    const int quad = lane >> 4, l16 = lane & 15;
    f32x4 acc[4] = {};

    float asc[4], adc[4];
#pragma unroll
    for (int ni = 0; ni < 4; ni++) {
        int gc = ni * 16 + l16;
        asc[ni] = (gc < 40) ? a2s[gc] : 0.f;
        adc[ni] = (gc < 40) ? a2d[gc] : 0.f;
    }

    for (int kc = 0; kc < 512; kc += 128) {
        {
            int row = tid >> 2, q = tid & 3;
            int gr = r0 + row;
            uint4 v0 = make_uint4(0u, 0u, 0u, 0u), v1 = v0, v2 = v0, v3 = v0;
            if (gr < M) {
                const u16* p = A + (size_t)gr * 512 + kc + q * 32;
                v0 = *(const uint4*)p;
                v1 = *(const uint4*)(p + 8);
                v2 = *(const uint4*)(p + 16);
                v3 = *(const uint4*)(p + 24);
            }
            u16* d = &As[row * LDT + q * 32];
            *(uint4*)(d + 0) = v0;
            *(uint4*)(d + 8) = v1;
            *(uint4*)(d + 16) = v2;
            *(uint4*)(d + 24) = v3;
        }
        {
            int row = tid >> 2, q = tid & 3;
            const u16* p = Bt + (size_t)row * 512 + kc + q * 32;
            uint4 v0 = *(const uint4*)p;
            uint4 v1 = *(const uint4*)(p + 8);
            uint4 v2 = *(const uint4*)(p + 16);
            uint4 v3 = *(const uint4*)(p + 24);
            u16* d = &Bs[row * LDT + q * 32];
            *(uint4*)(d + 0) = v0;
            *(uint4*)(d + 8) = v1;
            *(uint4*)(d + 16) = v2;
            *(uint4*)(d + 24) = v3;
        }
        __syncthreads();
#pragma unroll
        for (int kst = 0; kst < 4; kst++) {
            uint4 va = *(const uint4*)&As[(w * 16 + l16) * LDT + kst * 32 + quad * 8];
            bf16x8 af = __builtin_bit_cast(bf16x8, va);
#pragma unroll
            for (int ni = 0; ni < 4; ni++) {
                uint4 vb = *(const uint4*)&Bs[(ni * 16 + l16) * LDT + kst * 32 + quad * 8];
                bf16x8 bf = __builtin_bit_cast(bf16x8, vb);
                acc[ni] = __builtin_amdgcn_mfma_f32_16x16x32_bf16(af, bf, acc[ni], 0, 0, 0);
            }
        }
        __syncthreads();
    }
#pragma unroll
    for (int r = 0; r < 4; r++) {
        int gr = r0 + w * 16 + quad * 4 + r;
        float ps = 0.f, pd = 0.f;
#pragma unroll
        for (int ni = 0; ni < 4; ni++) {
            float v = acc[ni][r];
            ps = fmaf(v, asc[ni], ps);
            pd = fmaf(v, adc[ni], pd);
            int gc = ni * 16 + l16;
            if (gr < M && gc < 40) g[(size_t)gr * 40 + gc] = v;
        }
#pragma unroll
        for (int m = 8; m >= 1; m >>= 1) {
            ps += __shfl_xor(ps, m);
            pd += __shfl_xor(pd, m);
        }
        if (l16 == 0 && gr < M) {
            als[gr] = ps;
            ald[gr] = pd;
        }
    }
}

// ---------------- fused softmax+aggregation, layer 2 ----------------
__global__ __launch_bounds__(256) void agg2_fused(
    const int* __restrict__ offs, const int* __restrict__ esrc,
    const float* __restrict__ g, const float* __restrict__ als,
    const float* __restrict__ ald, const float* __restrict__ b2,
    float* __restrict__ out, int N) {
    int wid = blockIdx.x * 4 + (threadIdx.x >> 6);
    if (wid >= N) return;
    int lane = threadIdx.x & 63;
    int b = offs[wid], e = offs[wid + 1];
    float ad = ald[wid];
    float acc0 = 0.f, acc1 = 0.f, acc2 = 0.f, acc3 = 0.f, zs = 0.f;
    bool active = lane < 40;
    for (int jb = b; jb < e; jb += 64) {
        int nk = min(64, e - jb);
        int my = (jb + lane < e) ? esrc[jb + lane] : 0;
        int k = 0;
        for (; k + 8 <= nk; k += 8) {
            int s0 = __shfl(my, k + 0), s1 = __shfl(my, k + 1);
            int s2 = __shfl(my, k + 2), s3 = __shfl(my, k + 3);
            int s4 = __shfl(my, k + 4), s5 = __shfl(my, k + 5);
            int s6 = __shfl(my, k + 6), s7 = __shfl(my, k + 7);
            float g0 = active ? g[(size_t)s0 * 40 + lane] : 0.f;
            float g1 = active ? g[(size_t)s1 * 40 + lane] : 0.f;
            float g2 = active ? g[(size_t)s2 * 40 + lane] : 0.f;
            float g3 = active ? g[(size_t)s3 * 40 + lane] : 0.f;
            float g4 = active ? g[(size_t)s4 * 40 + lane] : 0.f;
            float g5 = active ? g[(size_t)s5 * 40 + lane] : 0.f;
            float g6 = active ? g[(size_t)s6 * 40 + lane] : 0.f;
            float g7 = active ? g[(size_t)s7 * 40 + lane] : 0.f;
            float w0 = edge_w(als[s0] + ad), w1 = edge_w(als[s1] + ad);
            float w2 = edge_w(als[s2] + ad), w3 = edge_w(als[s3] + ad);
            float w4 = edge_w(als[s4] + ad), w5 = edge_w(als[s5] + ad);
            float w6 = edge_w(als[s6] + ad), w7 = edge_w(als[s7] + ad);
            zs += ((w0 + w1) + (w2 + w3)) + ((w4 + w5) + (w6 + w7));
            acc0 = fmaf(w0, g0, acc0);
            acc1 = fmaf(w1, g1, acc1);
            acc2 = fmaf(w2, g2, acc2);
            acc3 = fmaf(w3, g3, acc3);
            acc0 = fmaf(w4, g4, acc0);
            acc1 = fmaf(w5, g5, acc1);
            acc2 = fmaf(w6, g6, acc2);
            acc3 = fmaf(w7, g7, acc3);
        }
        for (; k < nk; k++) {
            int s = __shfl(my, k);
            float gv = active ? g[(size_t)s * 40 + lane] : 0.f;
            float w = edge_w(als[s] + ad);
            zs += w;
            acc0 = fmaf(w, gv, acc0);
        }
    }
    if (active)
        out[(size_t)wid * 40 + lane] = ((acc0 + acc1) + (acc2 + acc3)) / zs + b2[lane];
}

// ---------------- host launch ----------------

extern "C" void kernel_launch(void* const* d_in, const int* in_sizes, int n_in,
                              void* d_out, int out_size, void* d_ws, size_t ws_size,
                              hipStream_t stream) {
    const float* x   = (const float*)d_in[0];
    const int*   ei  = (const int*)d_in[1];
    const float* W1  = (const float*)d_in[2];
    const float* a1s = (const float*)d_in[3];
    const float* a1d = (const float*)d_in[4];
    const float* b1  = (const float*)d_in[5];
    const float* W2  = (const float*)d_in[6];
    const float* a2s = (const float*)d_in[7];
    const float* a2d = (const float*)d_in[8];
    const float* b2  = (const float*)d_in[9];
    float* out = (float*)d_out;

    const int F = 128;
    const int N = in_sizes[0] / F;
    const int E = in_sizes[1] / 2;
    const int ET = E + N;
    const int Npad = (N + 63) & ~63;
    const int nScanBlk = (N + SCT * SCC - 1) / (SCT * SCC);
    const int T = nScanBlk * SCT;

    char* ws = (char*)d_ws;
    size_t off = 0;
    auto alloc = [&](size_t bytes) -> char* {
        char* p = ws + off;
        off += (bytes + 255) & ~(size_t)255;
        return p;
    };
    int*   esrc = (int*)alloc((size_t)ET * 4);
    int*   rank = (int*)alloc((size_t)E * 4);
    float* als1 = (float*)alloc((size_t)N * 8 * 4);
    float* ald1 = (float*)alloc((size_t)N * 8 * 4);
    float* als2 = (float*)alloc((size_t)N * 4);
    float* ald2 = (float*)alloc((size_t)N * 4);
    int*   deg  = (int*)alloc((size_t)N * 4);
    int*   offs = (int*)alloc((size_t)(N + 1) * 4);
    int*   tsum = (int*)alloc((size_t)T * 4);
    u16*   w1t  = (u16*)alloc((size_t)512 * 128 * 2);
    u16*   w2t  = (u16*)alloc((size_t)64 * 512 * 2);
    float* ws1  = (float*)alloc((size_t)1024 * 4);
    float* wd1  = (float*)alloc((size_t)1024 * 4);
    u16*   xb   = (u16*)alloc((size_t)N * 128 * 2);
    u16*   h2   = (u16*)alloc((size_t)N * 512 * 2);
    // y sized by pass count (1 pass of 8 heads if workspace allows, else 2x4)
    size_t y8 = (size_t)Npad * 8 * 128 * 2;
    size_t y4 = (size_t)Npad * 4 * 128 * 2;
    int NHp = (off + y8 + 4096 <= ws_size) ? 8 : 4;
    u16* y = (u16*)alloc(NHp == 8 ? y8 : y4);
    float* g = (float*)y;  // g [N,40] fp32 aliases y (y dead after gemm1b)

    const int TPB = 256;
    const int* e_src = ei;
    const int* e_dst = ei + E;

    // CSR + prep
    k0_kernel<<<(N + 2048 + TPB - 1) / TPB, TPB, 0, stream>>>(W1, a1s, a1d, ws1, wd1, deg, N);
    int setup_n = E + N * 32 + 512 * 128 + 64 * 512;
    setup_kernel<<<(setup_n + TPB - 1) / TPB, TPB, 0, stream>>>(
        e_dst, deg, rank, x, W1, W2, xb, w1t, w2t, E, N);
    scanA_kernel<<<nScanBlk, SCT, 0, stream>>>(deg, tsum, N);
    scanB_kernel<<<1, 1024, 0, stream>>>(tsum, offs, T, N);
    scanC_kernel<<<nScanBlk, SCT, 0, stream>>>(deg, tsum, offs, N);
    int scat_n = E + N + 8 * N;
    scatter_kernel<<<(scat_n + TPB - 1) / TPB, TPB, 0, stream>>>(
        e_src, e_dst, rank, offs, deg, esrc, (const u32*)xb, ws1, wd1, als1, ald1, E, N);

    // layer 1: aggregate x per head, then block-diagonal GEMM
    if (NHp == 8) {
        agg1x_kernel<8><<<(N + 3) / 4, 256, 0, stream>>>(
            offs, esrc, (const uint4*)xb, als1, ald1, y, N, 0);
        gemm1b_kernel<8><<<dim3((N + 63) / 64, 8), 256, 0, stream>>>(y, w1t, b1, h2, N, 0);
    } else {
        for (int p = 0; p < 2; p++) {
            agg1x_kernel<4><<<(N + 3) / 4, 256, 0, stream>>>(
                offs, esrc, (const uint4*)xb, als1, ald1, y, N, p * 4);
            gemm1b_kernel<4><<<dim3((N + 63) / 64, 4), 256, 0, stream>>>(y, w1t, b1, h2, N, p * 4);
        }
    }

    // layer 2
    gemm2_fused<<<(N + 63) / 64, 256, 0, stream>>>(h2, w2t, a2s, a2d, g, als2, ald2, N);
    agg2_fused<<<(N + 3) / 4, 256, 0, stream>>>(offs, esrc, g, als2, ald2, b2, out, N);
}

// Round 15
// 371.941 us; speedup vs baseline: 1.3593x; 1.1624x over previous
//
#include <hip/hip_runtime.h>
#include <hip/hip_bf16.h>
#include <stdint.h>

typedef unsigned short u16;
typedef unsigned int u32;
typedef __attribute__((ext_vector_type(8))) __bf16 bf16x8;
typedef __attribute__((ext_vector_type(4))) float f32x4;

#define NEG_SLOPE 0.2f
#define SCT 256   // threads per scan block
#define SCC 16    // elements per scan thread

__device__ __forceinline__ float bf2f(u16 u) {
    return __uint_as_float(((u32)u) << 16);
}
__device__ __forceinline__ u16 f2bf(float f) {
    u32 x = __float_as_uint(f);
    u32 r = (x + 0x7fffu + ((x >> 16) & 1u)) >> 16;  // round-to-nearest-even
    return (u16)r;
}
__device__ __forceinline__ float edge_w(float v) {
    v = v > 0.f ? v : NEG_SLOPE * v;  // LeakyReLU
    return __expf(v);
}

// ---------------- k0: deg=0 + projected attention vectors ----------------
// ws1[hd][k] = sum_c W1[k, hd*64+c] * a1s[hd*64+c]  (likewise wd1 with a1d)
__global__ void k0_kernel(const float* __restrict__ W1, const float* __restrict__ a1s,
                          const float* __restrict__ a1d, float* __restrict__ ws1,
                          float* __restrict__ wd1, int* __restrict__ deg, int N) {
    int t = blockIdx.x * blockDim.x + threadIdx.x;
    if (t < N) {
        deg[t] = 0;
    } else if (t < N + 2048) {
        int i = t - N;
        int which = i >> 10;        // 0: src, 1: dst
        int hd = (i & 1023) >> 7;   // head
        int k = i & 127;            // input channel
        const float* av = which ? a1d : a1s;
        float s = 0.f;
#pragma unroll 8
        for (int c = 0; c < 64; c++) s = fmaf(W1[k * 512 + hd * 64 + c], av[hd * 64 + c], s);
        (which ? wd1 : ws1)[hd * 128 + k] = s;
    }
}

// ---------------- setup: hist(+rank) + cast x->bf16 + transpose W1/W2 ----------------
// The histogram's atomicAdd return value IS the edge's rank within its dst
// bucket — stored to rank[] so the scatter pass needs no atomics at all.
__global__ void setup_kernel(const int* __restrict__ dst, int* __restrict__ deg,
                             int* __restrict__ rank,
                             const float* __restrict__ x, const float* __restrict__ W1,
                             const float* __restrict__ W2, u16* __restrict__ xb,
                             u16* __restrict__ w1t, u16* __restrict__ w2t,
                             int E, int N) {
    int t = blockIdx.x * blockDim.x + threadIdx.x;
    int rE = E;
    int r1 = rE + N * 32;          // x cast, float4 granules
    int r2 = r1 + 512 * 128;       // W1[128,512] -> w1t[512,128]
    int r3 = r2 + 64 * 512;        // W2[512,40] -> w2t[64,512] (rows 40..63 zero)
    if (t < rE) {
        rank[t] = atomicAdd(&deg[dst[t]], 1);
    } else if (t < r1) {
        int base = (t - rE) * 4;
        float4 v = *(const float4*)(x + base);
        xb[base + 0] = f2bf(v.x);
        xb[base + 1] = f2bf(v.y);
        xb[base + 2] = f2bf(v.z);
        xb[base + 3] = f2bf(v.w);
    } else if (t < r2) {
        int i = t - r1;
        int nn = i >> 7, k = i & 127;
        w1t[i] = f2bf(W1[k * 512 + nn]);
    } else if (t < r3) {
        int i = t - r2;
        int nn = i >> 9, k = i & 511;
        w2t[i] = (nn < 40) ? f2bf(W2[k * 40 + nn]) : (u16)0;
    }
}

// ---------------- 3-phase multi-block exclusive scan of (deg[i]+1) ----------------
__global__ void scanA_kernel(const int* __restrict__ deg, int* __restrict__ tsum, int N) {
    int t = blockIdx.x * SCT + threadIdx.x;
    int beg = t * SCC;
    int end = beg + SCC; if (end > N) end = N;
    int s = 0;
    for (int i = beg; i < end; i++) s += deg[i] + 1;  // +1 self loop
    tsum[t] = (beg < N) ? s : 0;
}

__global__ void scanB_kernel(int* __restrict__ tsum, int* __restrict__ offsets, int T, int N) {
    __shared__ int s[1024];
    int t = threadIdx.x;
    int chunk = (T + 1023) / 1024;
    int beg = t * chunk; if (beg > T) beg = T;
    int end = beg + chunk; if (end > T) end = T;
    int sum = 0;
    for (int i = beg; i < end; i++) sum += tsum[i];
    s[t] = sum;
    __syncthreads();
    for (int off = 1; off < 1024; off <<= 1) {
        int v = (t >= off) ? s[t - off] : 0;
        __syncthreads();
        s[t] += v;
        __syncthreads();
    }
    int run = s[t] - sum;  // exclusive prefix of this thread's chunk
    for (int i = beg; i < end; i++) {
        int v = tsum[i];
        tsum[i] = run;
        run += v;
    }
    if (t == 1023) offsets[N] = s[1023];  // grand total
}

__global__ void scanC_kernel(const int* __restrict__ deg, const int* __restrict__ tbase,
                             int* __restrict__ offsets, int N) {
    int t = blockIdx.x * SCT + threadIdx.x;
    int beg = t * SCC;
    int end = beg + SCC; if (end > N) end = N;
    int run = tbase[t];
    for (int i = beg; i < end; i++) {
        offsets[i] = run;
        run += deg[i] + 1;
    }
}

// scatter (atomic-free: idx = offs[dst] + precomputed rank) + fused logits1
// (als1/ald1 = xb . ws1/wd1 per (node, head))
__global__ void scatter_kernel(const int* __restrict__ src, const int* __restrict__ dst,
                               const int* __restrict__ rank, const int* __restrict__ offs,
                               const int* __restrict__ deg, int* __restrict__ esrc,
                               const u32* __restrict__ xb32,
                               const float* __restrict__ ws1, const float* __restrict__ wd1,
                               float* __restrict__ als1, float* __restrict__ ald1,
                               int E, int N) {
    int t = blockIdx.x * blockDim.x + threadIdx.x;
    if (t < E) {
        int d = dst[t];
        esrc[offs[d] + rank[t]] = src[t];
    } else if (t < E + N) {
        int i = t - E;
        esrc[offs[i] + deg[i]] = i;  // self loop takes the last slot
    } else if (t < E + N + 8 * N) {
        int idx = t - E - N;
        int n = idx >> 3, hd = idx & 7;
        const u32* xr = xb32 + (size_t)n * 64;
        const float* wsr = ws1 + hd * 128;
        const float* wdr = wd1 + hd * 128;
        float s = 0.f, d = 0.f;
#pragma unroll 8
        for (int kk = 0; kk < 64; kk++) {
            u32 v = xr[kk];
            float x0 = __uint_as_float(v << 16);
            float x1 = __uint_as_float(v & 0xffff0000u);
            s = fmaf(x0, wsr[2 * kk], fmaf(x1, wsr[2 * kk + 1], s));
            d = fmaf(x0, wdr[2 * kk], fmaf(x1, wdr[2 * kk + 1], d));
        }
        als1[idx] = s;
        ald1[idx] = d;
    }
}

// ---------------- agg1x: per-head weighted x aggregation (bf16 x) ----------------
// Exact r11 inner loop (measured 92 us @ VGPR 36): single acc[CPL], bf2f
// per-element decode, nested-fmaf 4-edge unroll. Only change vs r11:
// cacheable y store (NT was write-amplifying 177 vs 100 MB — r13 counters).
template <int NH>
__global__ __launch_bounds__(256) void agg1x_kernel(
    const int* __restrict__ offs, const int* __restrict__ esrc,
    const uint4* __restrict__ xb4, const float* __restrict__ als,
    const float* __restrict__ ald, u16* __restrict__ y, int N, int hd0) {
    constexpr int LPH = 64 / NH;    // lanes per head
    constexpr int CPL = 128 / LPH;  // channels per lane
    constexpr int NU4 = CPL / 8;    // uint4 (8 bf16) per lane per row
    int wid = blockIdx.x * 4 + (threadIdx.x >> 6);
    if (wid >= N) return;
    int lane = threadIdx.x & 63;
    int hd_l = lane / LPH;
    int chg = lane % LPH;
    int b = offs[wid], e = offs[wid + 1];
    float ad = ald[wid * 8 + hd0 + hd_l];
    float acc[CPL] = {};
    float zs = 0.f;
    const uint4* xr = xb4 + chg * NU4;
    for (int jb = b; jb < e; jb += 64) {
        int nk = min(64, e - jb);
        int my = (jb + lane < e) ? esrc[jb + lane] : 0;
        int k = 0;
        for (; k + 4 <= nk; k += 4) {
            int s0 = __shfl(my, k), s1 = __shfl(my, k + 1);
            int s2 = __shfl(my, k + 2), s3 = __shfl(my, k + 3);
            uint4 xa0[NU4], xa1[NU4], xa2[NU4], xa3[NU4];
#pragma unroll
            for (int j = 0; j < NU4; j++) {
                xa0[j] = xr[(size_t)s0 * 16 + j];
                xa1[j] = xr[(size_t)s1 * 16 + j];
                xa2[j] = xr[(size_t)s2 * 16 + j];
                xa3[j] = xr[(size_t)s3 * 16 + j];
            }
            float l0 = als[s0 * 8 + hd0 + hd_l];
            float l1 = als[s1 * 8 + hd0 + hd_l];
            float l2 = als[s2 * 8 + hd0 + hd_l];
            float l3 = als[s3 * 8 + hd0 + hd_l];
            float w0 = edge_w(l0 + ad), w1 = edge_w(l1 + ad);
            float w2 = edge_w(l2 + ad), w3 = edge_w(l3 + ad);
            zs += (w0 + w1) + (w2 + w3);
#pragma unroll
            for (int j = 0; j < NU4; j++) {
                const u16* p0 = (const u16*)&xa0[j];
                const u16* p1 = (const u16*)&xa1[j];
                const u16* p2 = (const u16*)&xa2[j];
                const u16* p3 = (const u16*)&xa3[j];
#pragma unroll
                for (int q = 0; q < 8; q++) {
                    int c = j * 8 + q;
                    acc[c] = fmaf(w0, bf2f(p0[q]), fmaf(w2, bf2f(p2[q]), acc[c]));
                    acc[c] = fmaf(w1, bf2f(p1[q]), fmaf(w3, bf2f(p3[q]), acc[c]));
                }
            }
        }
        for (; k < nk; k++) {
            int s = __shfl(my, k);
            uint4 xa[NU4];
#pragma unroll
            for (int j = 0; j < NU4; j++) xa[j] = xr[(size_t)s * 16 + j];
            float w = edge_w(als[s * 8 + hd0 + hd_l] + ad);
            zs += w;
#pragma unroll
            for (int j = 0; j < NU4; j++) {
                const u16* p = (const u16*)&xa[j];
#pragma unroll
                for (int q = 0; q < 8; q++) acc[j * 8 + q] = fmaf(w, bf2f(p[q]), acc[j * 8 + q]);
            }
        }
    }
    float zi = 1.f / zs;  // >0: self loop guarantees an edge
    u16 ob[CPL];
#pragma unroll
    for (int c = 0; c < CPL; c++) ob[c] = f2bf(acc[c] * zi);
    u16* dst = y + ((size_t)wid * NH + hd_l) * 128 + chg * CPL;
#pragma unroll
    for (int j = 0; j < CPL / 8; j++) {
        uint4 pv;
        pv.x = (u32)ob[j * 8 + 0] | ((u32)ob[j * 8 + 1] << 16);
        pv.y = (u32)ob[j * 8 + 2] | ((u32)ob[j * 8 + 3] << 16);
        pv.z = (u32)ob[j * 8 + 4] | ((u32)ob[j * 8 + 5] << 16);
        pv.w = (u32)ob[j * 8 + 6] | ((u32)ob[j * 8 + 7] << 16);
        *((uint4*)dst + j) = pv;  // cacheable: y is consumed once by gemm1b
    }
}

// ---------------- gemm1b: per-head y @ W1_head + b1 -> relu -> h2 ----------------
template <int NH>
__global__ __launch_bounds__(256) void gemm1b_kernel(
    const u16* __restrict__ y, const u16* __restrict__ w1t,
    const float* __restrict__ b1, u16* __restrict__ h2, int M, int hd0) {
    constexpr int LDT = 136;  // 128 + 8 pad
    __shared__ u16 As[64 * LDT];
    __shared__ u16 Bs[64 * LDT];
    const int tid = threadIdx.x;
    const int r0 = blockIdx.x * 64;
    const int hh = blockIdx.y;
    const int head = hd0 + hh;
    const int lane = tid & 63, w = tid >> 6;
    const int quad = lane >> 4, l16 = lane & 15;
    {
        int row = tid >> 2, q = tid & 3;
        int gr = r0 + row;
        uint4 v0 = make_uint4(0u, 0u, 0u, 0u), v1 = v0, v2 = v0, v3 = v0;
        if (gr < M) {
            const u16* p = y + ((size_t)gr * NH + hh) * 128 + q * 32;
            v0 = *(const uint4*)p;
            v1 = *(const uint4*)(p + 8);
            v2 = *(const uint4*)(p + 16);
            v3 = *(const uint4*)(p + 24);
        }
        u16* d = &As[row * LDT + q * 32];
        *(uint4*)(d + 0) = v0;
        *(uint4*)(d + 8) = v1;
        *(uint4*)(d + 16) = v2;
        *(uint4*)(d + 24) = v3;
    }
    {
        int row = tid >> 2, q = tid & 3;
        const u16* p = w1t + ((size_t)(head * 64 + row)) * 128 + q * 32;
        uint4 v0 = *(const uint4*)p;
        uint4 v1 = *(const uint4*)(p + 8);
        uint4 v2 = *(const uint4*)(p + 16);
        uint4 v3 = *(const uint4*)(p + 24);
        u16* d = &Bs[row * LDT + q * 32];
        *(uint4*)(d + 0) = v0;
        *(uint4*)(d + 8) = v1;
        *(uint4*)(d + 16) = v2;
        *(uint4*)(d + 24) = v3;
    }
    __syncthreads();
    f32x4 acc[4] = {};
#pragma unroll
    for (int kst = 0; kst < 4; kst++) {
        uint4 va = *(const uint4*)&As[(w * 16 + l16) * LDT + kst * 32 + quad * 8];
        bf16x8 af = __builtin_bit_cast(bf16x8, va);
#pragma unroll
        for (int ni = 0; ni < 4; ni++) {
            uint4 vb = *(const uint4*)&Bs[(ni * 16 + l16) * LDT + kst * 32 + quad * 8];
            bf16x8 bf = __builtin_bit_cast(bf16x8, vb);
            acc[ni] = __builtin_amdgcn_mfma_f32_16x16x32_bf16(af, bf, acc[ni], 0, 0, 0);
        }
    }
#pragma unroll
    for (int r = 0; r < 4; r++) {
        int gr = r0 + w * 16 + quad * 4 + r;
        if (gr >= M) continue;
#pragma unroll
        for (int ni = 0; ni < 4; ni++) {
            int gc = head * 64 + ni * 16 + l16;
            float v = acc[ni][r] + b1[gc];
            v = v > 0.f ? v : 0.f;  // inter-layer ReLU
            h2[(size_t)gr * 512 + gc] = f2bf(v);
        }
    }
}

// ---------------- GEMM2 (h2 @ W2 -> g fp32) + fused logits2 ----------------
__global__ __launch_bounds__(256) void gemm2_fused(
    const u16* __restrict__ A, const u16* __restrict__ Bt,
    const float* __restrict__ a2s, const float* __restrict__ a2d,
    float* __restrict__ g, float* __restrict__ als, float* __restrict__ ald, int M) {
    constexpr int LDT = 136;  // 128 + 8 pad
    __shared__ u16 As[64 * LDT];
    __shared__ u16 Bs[64 * LDT];
    const int tid = threadIdx.x;
    const int r0 = blockIdx.x * 64;
    const int lane = tid & 63, w = tid >> 6;
    const int quad = lane >> 4, l16 = lane & 15;
    f32x4 acc[4] = {};

    float asc[4], adc[4];
#pragma unroll
    for (int ni = 0; ni < 4; ni++) {
        int gc = ni * 16 + l16;
        asc[ni] = (gc < 40) ? a2s[gc] : 0.f;
        adc[ni] = (gc < 40) ? a2d[gc] : 0.f;
    }

    for (int kc = 0; kc < 512; kc += 128) {
        {
            int row = tid >> 2, q = tid & 3;
            int gr = r0 + row;
            uint4 v0 = make_uint4(0u, 0u, 0u, 0u), v1 = v0, v2 = v0, v3 = v0;
            if (gr < M) {
                const u16* p = A + (size_t)gr * 512 + kc + q * 32;
                v0 = *(const uint4*)p;
                v1 = *(const uint4*)(p + 8);
                v2 = *(const uint4*)(p + 16);
                v3 = *(const uint4*)(p + 24);
            }
            u16* d = &As[row * LDT + q * 32];
            *(uint4*)(d + 0) = v0;
            *(uint4*)(d + 8) = v1;
            *(uint4*)(d + 16) = v2;
            *(uint4*)(d + 24) = v3;
        }
        {
            int row = tid >> 2, q = tid & 3;
            const u16* p = Bt + (size_t)row * 512 + kc + q * 32;
            uint4 v0 = *(const uint4*)p;
            uint4 v1 = *(const uint4*)(p + 8);
            uint4 v2 = *(const uint4*)(p + 16);
            uint4 v3 = *(const uint4*)(p + 24);
            u16* d = &Bs[row * LDT + q * 32];
            *(uint4*)(d + 0) = v0;
            *(uint4*)(d + 8) = v1;
            *(uint4*)(d + 16) = v2;
            *(uint4*)(d + 24) = v3;
        }
        __syncthreads();
#pragma unroll
        for (int kst = 0; kst < 4; kst++) {
            uint4 va = *(const uint4*)&As[(w * 16 + l16) * LDT + kst * 32 + quad * 8];
            bf16x8 af = __builtin_bit_cast(bf16x8, va);
#pragma unroll
            for (int ni = 0; ni < 4; ni++) {
                uint4 vb = *(const uint4*)&Bs[(ni * 16 + l16) * LDT + kst * 32 + quad * 8];
                bf16x8 bf = __builtin_bit_cast(bf16x8, vb);
                acc[ni] = __builtin_amdgcn_mfma_f32_16x16x32_bf16(af, bf, acc[ni], 0, 0, 0);
            }
        }
        __syncthreads();
    }
#pragma unroll
    for (int r = 0; r < 4; r++) {
        int gr = r0 + w * 16 + quad * 4 + r;
        float ps = 0.f, pd = 0.f;
#pragma unroll
        for (int ni = 0; ni < 4; ni++) {
            float v = acc[ni][r];
            ps = fmaf(v, asc[ni], ps);
            pd = fmaf(v, adc[ni], pd);
            int gc = ni * 16 + l16;
            if (gr < M && gc < 40) g[(size_t)gr * 40 + gc] = v;
        }
#pragma unroll
        for (int m = 8; m >= 1; m >>= 1) {
            ps += __shfl_xor(ps, m);
            pd += __shfl_xor(pd, m);
        }
        if (l16 == 0 && gr < M) {
            als[gr] = ps;
            ald[gr] = pd;
        }
    }
}

// ---------------- fused softmax+aggregation, layer 2 ----------------
__global__ __launch_bounds__(256) void agg2_fused(
    const int* __restrict__ offs, const int* __restrict__ esrc,
    const float* __restrict__ g, const float* __restrict__ als,
    const float* __restrict__ ald, const float* __restrict__ b2,
    float* __restrict__ out, int N) {
    int wid = blockIdx.x * 4 + (threadIdx.x >> 6);
    if (wid >= N) return;
    int lane = threadIdx.x & 63;
    int b = offs[wid], e = offs[wid + 1];
    float ad = ald[wid];
    float acc0 = 0.f, acc1 = 0.f, acc2 = 0.f, acc3 = 0.f, zs = 0.f;
    bool active = lane < 40;
    for (int jb = b; jb < e; jb += 64) {
        int nk = min(64, e - jb);
        int my = (jb + lane < e) ? esrc[jb + lane] : 0;
        int k = 0;
        for (; k + 8 <= nk; k += 8) {
            int s0 = __shfl(my, k + 0), s1 = __shfl(my, k + 1);
            int s2 = __shfl(my, k + 2), s3 = __shfl(my, k + 3);
            int s4 = __shfl(my, k + 4), s5 = __shfl(my, k + 5);
            int s6 = __shfl(my, k + 6), s7 = __shfl(my, k + 7);
            float g0 = active ? g[(size_t)s0 * 40 + lane] : 0.f;
            float g1 = active ? g[(size_t)s1 * 40 + lane] : 0.f;
            float g2 = active ? g[(size_t)s2 * 40 + lane] : 0.f;
            float g3 = active ? g[(size_t)s3 * 40 + lane] : 0.f;
            float g4 = active ? g[(size_t)s4 * 40 + lane] : 0.f;
            float g5 = active ? g[(size_t)s5 * 40 + lane] : 0.f;
            float g6 = active ? g[(size_t)s6 * 40 + lane] : 0.f;
            float g7 = active ? g[(size_t)s7 * 40 + lane] : 0.f;
            float w0 = edge_w(als[s0] + ad), w1 = edge_w(als[s1] + ad);
            float w2 = edge_w(als[s2] + ad), w3 = edge_w(als[s3] + ad);
            float w4 = edge_w(als[s4] + ad), w5 = edge_w(als[s5] + ad);
            float w6 = edge_w(als[s6] + ad), w7 = edge_w(als[s7] + ad);
            zs += ((w0 + w1) + (w2 + w3)) + ((w4 + w5) + (w6 + w7));
            acc0 = fmaf(w0, g0, acc0);
            acc1 = fmaf(w1, g1, acc1);
            acc2 = fmaf(w2, g2, acc2);
            acc3 = fmaf(w3, g3, acc3);
            acc0 = fmaf(w4, g4, acc0);
            acc1 = fmaf(w5, g5, acc1);
            acc2 = fmaf(w6, g6, acc2);
            acc3 = fmaf(w7, g7, acc3);
        }
        for (; k < nk; k++) {
            int s = __shfl(my, k);
            float gv = active ? g[(size_t)s * 40 + lane] : 0.f;
            float w = edge_w(als[s] + ad);
            zs += w;
            acc0 = fmaf(w, gv, acc0);
        }
    }
    if (active)
        out[(size_t)wid * 40 + lane] = ((acc0 + acc1) + (acc2 + acc3)) / zs + b2[lane];
}

// ---------------- host launch ----------------

extern "C" void kernel_launch(void* const* d_in, const int* in_sizes, int n_in,
                              void* d_out, int out_size, void* d_ws, size_t ws_size,
                              hipStream_t stream) {
    const float* x   = (const float*)d_in[0];
    const int*   ei  = (const int*)d_in[1];
    const float* W1  = (const float*)d_in[2];
    const float* a1s = (const float*)d_in[3];
    const float* a1d = (const float*)d_in[4];
    const float* b1  = (const float*)d_in[5];
    const float* W2  = (const float*)d_in[6];
    const float* a2s = (const float*)d_in[7];
    const float* a2d = (const float*)d_in[8];
    const float* b2  = (const float*)d_in[9];
    float* out = (float*)d_out;

    const int F = 128;
    const int N = in_sizes[0] / F;
    const int E = in_sizes[1] / 2;
    const int ET = E + N;
    const int Npad = (N + 63) & ~63;
    const int nScanBlk = (N + SCT * SCC - 1) / (SCT * SCC);
    const int T = nScanBlk * SCT;

    char* ws = (char*)d_ws;
    size_t off = 0;
    auto alloc = [&](size_t bytes) -> char* {
        char* p = ws + off;
        off += (bytes + 255) & ~(size_t)255;
        return p;
    };
    int*   esrc = (int*)alloc((size_t)ET * 4);
    int*   rank = (int*)alloc((size_t)E * 4);
    float* als1 = (float*)alloc((size_t)N * 8 * 4);
    float* ald1 = (float*)alloc((size_t)N * 8 * 4);
    float* als2 = (float*)alloc((size_t)N * 4);
    float* ald2 = (float*)alloc((size_t)N * 4);
    int*   deg  = (int*)alloc((size_t)N * 4);
    int*   offs = (int*)alloc((size_t)(N + 1) * 4);
    int*   tsum = (int*)alloc((size_t)T * 4);
    u16*   w1t  = (u16*)alloc((size_t)512 * 128 * 2);
    u16*   w2t  = (u16*)alloc((size_t)64 * 512 * 2);
    float* ws1  = (float*)alloc((size_t)1024 * 4);
    float* wd1  = (float*)alloc((size_t)1024 * 4);
    u16*   xb   = (u16*)alloc((size_t)N * 128 * 2);
    u16*   h2   = (u16*)alloc((size_t)N * 512 * 2);
    // y sized by pass count (1 pass of 8 heads if workspace allows, else 2x4)
    size_t y8 = (size_t)Npad * 8 * 128 * 2;
    size_t y4 = (size_t)Npad * 4 * 128 * 2;
    int NHp = (off + y8 + 4096 <= ws_size) ? 8 : 4;
    u16* y = (u16*)alloc(NHp == 8 ? y8 : y4);
    float* g = (float*)y;  // g [N,40] fp32 aliases y (y dead after gemm1b)

    const int TPB = 256;
    const int* e_src = ei;
    const int* e_dst = ei + E;

    // CSR + prep
    k0_kernel<<<(N + 2048 + TPB - 1) / TPB, TPB, 0, stream>>>(W1, a1s, a1d, ws1, wd1, deg, N);
    int setup_n = E + N * 32 + 512 * 128 + 64 * 512;
    setup_kernel<<<(setup_n + TPB - 1) / TPB, TPB, 0, stream>>>(
        e_dst, deg, rank, x, W1, W2, xb, w1t, w2t, E, N);
    scanA_kernel<<<nScanBlk, SCT, 0, stream>>>(deg, tsum, N);
    scanB_kernel<<<1, 1024, 0, stream>>>(tsum, offs, T, N);
    scanC_kernel<<<nScanBlk, SCT, 0, stream>>>(deg, tsum, offs, N);
    int scat_n = E + N + 8 * N;
    scatter_kernel<<<(scat_n + TPB - 1) / TPB, TPB, 0, stream>>>(
        e_src, e_dst, rank, offs, deg, esrc, (const u32*)xb, ws1, wd1, als1, ald1, E, N);

    // layer 1: aggregate x per head, then block-diagonal GEMM
    if (NHp == 8) {
        agg1x_kernel<8><<<(N + 3) / 4, 256, 0, stream>>>(
            offs, esrc, (const uint4*)xb, als1, ald1, y, N, 0);
        gemm1b_kernel<8><<<dim3((N + 63) / 64, 8), 256, 0, stream>>>(y, w1t, b1, h2, N, 0);
    } else {
        for (int p = 0; p < 2; p++) {
            agg1x_kernel<4><<<(N + 3) / 4, 256, 0, stream>>>(
                offs, esrc, (const uint4*)xb, als1, ald1, y, N, p * 4);
            gemm1b_kernel<4><<<dim3((N + 63) / 64, 4), 256, 0, stream>>>(y, w1t, b1, h2, N, p * 4);
        }
    }

    // layer 2
    gemm2_fused<<<(N + 63) / 64, 256, 0, stream>>>(h2, w2t, a2s, a2d, g, als2, ald2, N);
    agg2_fused<<<(N + 3) / 4, 256, 0, stream>>>(offs, esrc, g, als2, ald2, b2, out, N);
}